// Round 7
// baseline (306.486 us; speedup 1.0000x reference)
//
#include <hip/hip_runtime.h>

// Shapes fixed by the reference: B=64, N=576, C=1024.
#define B_ 64
#define N_ 576
#define C_ 1024
#define SLICES 8                      // blocks per batch; each owns 72 output rows
#define SLICE_ROWS (N_ / SLICES)      // 72
#define TPB 512                       // 8 waves; grid=512 -> 2 blocks/CU co-resident
#define WAVES (TPB / 64)              // 8
#define ROWS_A (N_ / WAVES)           // 72 logit rows per wave (phase A)
#define ROWS_B (SLICE_ROWS / WAVES)   // 9 output rows per wave (phase B)
#define NXCD 8

typedef float v4f __attribute__((ext_vector_type(4)));

// One launch, ZERO cross-block sync (rounds 1-4: every cross-block protocol
// cost 100+ us). Redundant logit compute: each slice-block recomputes all 576
// logits of its batch into LDS (bit-identical expression -> consistent masks,
// no communication), block-local barrier, then ranks + copies its own slice.
//
// Round-5 lesson: slice-blocks must share an XCD or each XCD's L2 refetches
// the slab (FETCH was 2.15x V). Swizzle keeps a batch's blocks on one XCD
// (blockIdx%8 assumed = XCD under round-robin dispatch; if wrong, harmless).
//
// Round-6 lesson: grid=256 (1 block/CU) serializes phase A (L2-bound read,
// ~17us/XCD) against phase B (HBM-bound NT write, ~23us/XCD) -> 98us at 2.5
// TB/s, occupancy 38%, VALUBusy 10% = latency-bound. Fix: TPB=512/SLICES=8 ->
// 2 co-resident blocks per CU; their phases desync so the read and write
// streams run CONCURRENTLY. L2 redundancy doubles (72->144MB/XCD, ~33us) but
// now overlaps the write instead of adding to it.
__global__ __launch_bounds__(TPB) void k_onepass(const float* __restrict__ V,
                                                 const float* __restrict__ W,
                                                 const float* __restrict__ token_budget,
                                                 float* __restrict__ out_feat,
                                                 float* __restrict__ out_mask) {
    __shared__ float sl[N_];
    const int p = blockIdx.x;
    const int xcd = p & (NXCD - 1);           // assumed XCD under round-robin dispatch
    const int k = p >> 3;                     // 0..63 within XCD
    const int b = xcd * (B_ / NXCD) + (k & 7);    // batch: 8 per XCD
    const int r = k >> 3;                     // slice 0..7 (same xcd for all 8)
    const int t = threadIdx.x;
    const int w = t >> 6, l = t & 63;

    // Hoist the W fragment: identical for every row. Only first C floats
    // matter for ranking (budget-embedding term + bias are per-b constants ->
    // rank-preserving, dropped; validated rounds 0-6).
    const v4f* w4 = (const v4f*)W;
    v4f wr[4];
#pragma unroll
    for (int it = 0; it < 4; ++it) wr[it] = w4[l + it * 64];

    const float* Vb = V + (size_t)b * N_ * C_;

    // ---- phase A: all 576 logits of batch b (one wave per row, 72 rows/wave).
    // EXACT accumulation order of every passing version -> bit-identical logits.
#pragma unroll 4
    for (int j = 0; j < ROWS_A; ++j) {
        const int n = w * ROWS_A + j;
        const v4f* v4 = (const v4f*)(Vb + (size_t)n * C_);
        float acc = 0.f;
#pragma unroll
        for (int it = 0; it < 4; ++it) {
            v4f v = v4[l + it * 64];          // coalesced 1KB/instruction
            acc += v.x * wr[it].x + v.y * wr[it].y + v.z * wr[it].z + v.w * wr[it].w;
        }
#pragma unroll
        for (int off = 32; off; off >>= 1) acc += __shfl_xor(acc, off, 64);
        if (l == 0) sl[n] = acc;
    }
    __syncthreads();                          // block-local: the only barrier

    int K = (int)(token_budget[b] * (float)N_);   // astype(int32) truncates toward zero
    K = K < 1 ? 1 : (K > N_ ? N_ : K);

    // ---- phase B: rank + copy this block's 72-row slice (9 rows/wave) ----
    for (int j = 0; j < ROWS_B; ++j) {
        const int n = r * SLICE_ROWS + w * ROWS_B + j;   // batch-local row
        const float ln = sl[n];
        int rank = 0;
#pragma unroll
        for (int i = 0; i < N_ / 64; ++i) {   // 9 iters; tie -> lower index
            int m = l + 64 * i;               // (jnp.argmax first-occurrence)
            float lm = sl[m];
            rank += (lm > ln) || (lm == ln && m < n);
        }
#pragma unroll
        for (int off = 32; off; off >>= 1) rank += __shfl_xor(rank, off, 64);

        const size_t row = (size_t)b * N_ + n;
        const float mv = (rank < K) ? 1.0f : 0.0f;   // wave-uniform after reduce
        if (l == 0) out_mask[row] = mv;

        // copy/zero; kept-row re-read is L2-hot (phase A streamed the slab).
        // NT stores bypass LLC -> V stays resident for the sibling slices.
        const v4f* v4 = (const v4f*)(V + row * C_);
        v4f* o4 = (v4f*)(out_feat + row * C_);
        if (mv != 0.0f) {
#pragma unroll
            for (int it = 0; it < 4; ++it)
                __builtin_nontemporal_store(v4[l + it * 64], &o4[l + it * 64]);
        } else {
            const v4f z = {0.f, 0.f, 0.f, 0.f};
#pragma unroll
            for (int it = 0; it < 4; ++it)
                __builtin_nontemporal_store(z, &o4[l + it * 64]);
        }
    }
}

extern "C" void kernel_launch(void* const* d_in, const int* in_sizes, int n_in,
                              void* d_out, int out_size, void* d_ws, size_t ws_size,
                              hipStream_t stream) {
    const float* V  = (const float*)d_in[0];  // [B,N,C]
    const float* tb = (const float*)d_in[1];  // [B]
    // d_in[2] (budget_embedding), W[C:2C), bias: per-row rank-preserving constants.
    const float* W  = (const float*)d_in[3];  // [1,2C]

    float* out_feat = (float*)d_out;                         // [B,N,C]
    float* out_mask = (float*)d_out + (size_t)B_ * N_ * C_;  // [B,N]

    // 512 blocks (2 per CU), 8 waves each; no workspace, no memset, no sync.
    k_onepass<<<B_ * SLICES, TPB, 0, stream>>>(V, W, tb, out_feat, out_mask);
}

// Round 8
// 292.810 us; speedup vs baseline: 1.0467x; 1.0467x over previous
//
#include <hip/hip_runtime.h>

// Shapes fixed by the reference: B=64, N=576, C=1024.
#define B_ 64
#define N_ 576
#define C_ 1024
#define SLICES 4                      // blocks per batch; each owns 144 output rows
#define SLICE_ROWS (N_ / SLICES)      // 144
#define TPB 1024                      // 16 waves; grid=256 -> 1 block/CU
#define WAVES (TPB / 64)              // 16
#define ROWS_A (N_ / WAVES)           // 36 logit rows per wave (phase A)
#define ROWS_B (SLICE_ROWS / WAVES)   // 9 output rows per wave (phase B)
#define NXCD 8

typedef float v4f __attribute__((ext_vector_type(4)));

// One launch, ZERO cross-block sync (rounds 1-4: every cross-block protocol
// cost 100+ us). Redundant logit compute per slice-block; same-XCD swizzle
// (round 5: else FETCH=2.15x V; with it, 103MB).
//
// Round-7 lesson: co-resident symmetric blocks do NOT desync -- both sit in
// the same phase, so "2 blocks/CU for overlap" only doubled the redundancy
// (98->130us). Overlap must be BUILT IN, not hoped for.
//
// This version: COPY DURING PHASE A. Each own-slice row is NT-stored straight
// from the dot-product registers (zero extra reads), making phase A a
// concurrent read+write stream. Phase B then only writes zeros over dropped
// rows (no reads). Ordering: __syncthreads() drains vmcnt(0) before
// s_barrier, so the copy is acked before any phase-B zero-store to the same
// line. Cost: dropped rows written twice (+~74MB expected) -- cheaper than
// the 58us of serialization it removes.
__global__ __launch_bounds__(TPB) void k_onepass(const float* __restrict__ V,
                                                 const float* __restrict__ W,
                                                 const float* __restrict__ token_budget,
                                                 float* __restrict__ out_feat,
                                                 float* __restrict__ out_mask) {
    __shared__ float sl[N_];
    const int p = blockIdx.x;
    const int xcd = p & (NXCD - 1);           // assumed XCD under round-robin dispatch
    const int k = p >> 3;                     // 0..31 within XCD
    const int b = xcd * (B_ / NXCD) + (k & 7);    // batch: 8 per XCD
    const int r = k >> 3;                     // slice 0..3 (same xcd for all 4)
    const int t = threadIdx.x;
    const int w = t >> 6, l = t & 63;

    // Hoist the W fragment: identical for every row. Only first C floats
    // matter for ranking (budget-embedding term + bias are per-b constants ->
    // rank-preserving, dropped; validated rounds 0-7).
    const v4f* w4 = (const v4f*)W;
    v4f wr[4];
#pragma unroll
    for (int it = 0; it < 4; ++it) wr[it] = w4[l + it * 64];

    const float* Vb = V + (size_t)b * N_ * C_;
    // Contiguous row<->wave map makes slice ownership wave-uniform AND
    // loop-invariant: waves 4r..4r+3 own exactly slice r's 144 rows.
    const bool mine = ((w >> 2) == r);

    // ---- phase A: all 576 logits; own-slice rows also copied to out_feat
    // straight from the loaded registers (read stream + write stream overlap).
    // EXACT accumulation order of every passing version -> bit-identical logits.
#pragma unroll 2
    for (int j = 0; j < ROWS_A; ++j) {
        const int n = w * ROWS_A + j;
        const v4f* v4 = (const v4f*)(Vb + (size_t)n * C_);
        v4f v[4];
        float acc = 0.f;
#pragma unroll
        for (int it = 0; it < 4; ++it) {
            v[it] = v4[l + it * 64];          // coalesced 1KB/instruction
            acc += v[it].x * wr[it].x + v[it].y * wr[it].y +
                   v[it].z * wr[it].z + v[it].w * wr[it].w;
        }
#pragma unroll
        for (int off = 32; off; off >>= 1) acc += __shfl_xor(acc, off, 64);
        if (l == 0) sl[n] = acc;
        if (mine) {                            // wave-uniform, no divergence
            v4f* o4 = (v4f*)(out_feat + ((size_t)b * N_ + n) * C_);
#pragma unroll
            for (int it = 0; it < 4; ++it)
                __builtin_nontemporal_store(v[it], &o4[l + it * 64]);
        }
    }
    __syncthreads();          // drains vmcnt(0): copies acked before overwrites

    int K = (int)(token_budget[b] * (float)N_);   // astype(int32) truncates toward zero
    K = K < 1 ? 1 : (K > N_ ? N_ : K);

    // ---- phase B: rank my slice (9 rows/wave); dropped rows -> overwrite
    // with zeros (NO reads); kept rows already written in phase A. ----
    for (int j = 0; j < ROWS_B; ++j) {
        const int n = r * SLICE_ROWS + w * ROWS_B + j;   // batch-local row
        const float ln = sl[n];
        int rank = 0;
#pragma unroll
        for (int i = 0; i < N_ / 64; ++i) {   // 9 iters; tie -> lower index
            int m = l + 64 * i;               // (jnp.argmax first-occurrence)
            float lm = sl[m];
            rank += (lm > ln) || (lm == ln && m < n);
        }
#pragma unroll
        for (int off = 32; off; off >>= 1) rank += __shfl_xor(rank, off, 64);

        const size_t row = (size_t)b * N_ + n;
        const float mv = (rank < K) ? 1.0f : 0.0f;   // wave-uniform after reduce
        if (l == 0) out_mask[row] = mv;

        if (mv == 0.0f) {
            v4f* o4 = (v4f*)(out_feat + row * C_);
            const v4f z = {0.f, 0.f, 0.f, 0.f};
#pragma unroll
            for (int it = 0; it < 4; ++it)
                __builtin_nontemporal_store(z, &o4[l + it * 64]);
        }
    }
}

extern "C" void kernel_launch(void* const* d_in, const int* in_sizes, int n_in,
                              void* d_out, int out_size, void* d_ws, size_t ws_size,
                              hipStream_t stream) {
    const float* V  = (const float*)d_in[0];  // [B,N,C]
    const float* tb = (const float*)d_in[1];  // [B]
    // d_in[2] (budget_embedding), W[C:2C), bias: per-row rank-preserving constants.
    const float* W  = (const float*)d_in[3];  // [1,2C]

    float* out_feat = (float*)d_out;                         // [B,N,C]
    float* out_mask = (float*)d_out + (size_t)B_ * N_ * C_;  // [B,N]

    // 256 blocks (1 per CU), 16 waves each; no workspace, no memset, no sync.
    k_onepass<<<B_ * SLICES, TPB, 0, stream>>>(V, W, tb, out_feat, out_mask);
}